// Round 3
// baseline (2118.360 us; speedup 1.0000x reference)
//
#include <hip/hip_runtime.h>
#include <cstddef>

#define DIMC   768
#define HEADS  12
#define HD     64
#define BATCH  8
#define SEQ    4096
#define MTOK   (BATCH*SEQ)     // 32768
#define THREEC (3*DIMC)        // 2304
#define BHN    (BATCH*HEADS)   // 96
#define NCHUNK 8               // token chunks per (b,h)
#define CHTOK  (SEQ/NCHUNK)    // 512 tokens per chunk
#define EPSN   1e-12f

// ---------------------------------------------------------------------------
// Stage 1: per (b, h, chunk) block, compute q,k,v for 512 tokens ON THE FLY
// (never stored to global), accumulate:
//   dqp[bid][d] = sum_tok |q|,  dkp[bid][d] = sum_tok |k|,
//   kvp[bid][d][e] = sum_tok k[t][d] * v[t][e]
// 8 sub-tiles of 64 tokens; per sub-tile a [64 tok x 192 out, K=768] GEMM.
// ---------------------------------------------------------------------------
__global__ __launch_bounds__(256)
void qkv_stage1(const float* __restrict__ x, const float* __restrict__ w_qkv,
                float* __restrict__ kvp, float* __restrict__ dqp,
                float* __restrict__ dkp) {
  const int bid = blockIdx.x;
  const int bh = bid >> 3, chunk = bid & 7;
  const int b = bh / HEADS, h = bh % HEADS;
  const int tid = threadIdx.x;
  const int tx = tid & 15, ty = tid >> 4;
  const int lr = tid >> 2;            // 0..63
  const int lc4 = (tid & 3) << 2;     // 0,4,8,12

  __shared__ float Xs[16][68];        // [k][tok]
  __shared__ float Ws[16][196];       // [k][out 0..63=q,64..127=k,128..191=v]
  __shared__ float KVsub[64][132];    // [tok][0..63=k, 64..127=v]; reused as red

  float kv_acc[4][4] = {};
  float dq_local[4] = {}, dk_local[4] = {};

  for (int sub = 0; sub < 8; ++sub) {
    const size_t tok0 = (size_t)(b * SEQ + chunk * CHTOK + sub * 64);
    const float* xp = x + tok0 * DIMC;
    float accq[4][4] = {}, acck[4][4] = {}, accv[4][4] = {};
    for (int k0 = 0; k0 < DIMC; k0 += 16) {
      __syncthreads();
      // stage X tile [64 tok x 16 k] transposed
      {
        float4 v4 = *(const float4*)&xp[(size_t)lr * DIMC + k0 + lc4];
        Xs[lc4+0][lr] = v4.x; Xs[lc4+1][lr] = v4.y;
        Xs[lc4+2][lr] = v4.z; Xs[lc4+3][lr] = v4.w;
      }
      // stage W tile [192 out x 16 k] transposed (q,k,v row groups)
      #pragma unroll
      for (int s = 0; s < 3; ++s) {
        const int grow = s * DIMC + h * HD + lr;
        float4 v4 = *(const float4*)&w_qkv[(size_t)grow * DIMC + k0 + lc4];
        Ws[lc4+0][s*64+lr] = v4.x; Ws[lc4+1][s*64+lr] = v4.y;
        Ws[lc4+2][s*64+lr] = v4.z; Ws[lc4+3][s*64+lr] = v4.w;
      }
      __syncthreads();
      #pragma unroll
      for (int kk = 0; kk < 16; ++kk) {
        float4 a4 = *(const float4*)&Xs[kk][ty << 2];
        float4 q4 = *(const float4*)&Ws[kk][tx << 2];
        float4 k4 = *(const float4*)&Ws[kk][64 + (tx << 2)];
        float4 v4 = *(const float4*)&Ws[kk][128 + (tx << 2)];
        float ar[4] = {a4.x, a4.y, a4.z, a4.w};
        float qr[4] = {q4.x, q4.y, q4.z, q4.w};
        float kr[4] = {k4.x, k4.y, k4.z, k4.w};
        float vr[4] = {v4.x, v4.y, v4.z, v4.w};
        #pragma unroll
        for (int i = 0; i < 4; ++i)
          #pragma unroll
          for (int j = 0; j < 4; ++j) {
            accq[i][j] = fmaf(ar[i], qr[j], accq[i][j]);
            acck[i][j] = fmaf(ar[i], kr[j], acck[i][j]);
            accv[i][j] = fmaf(ar[i], vr[j], accv[i][j]);
          }
      }
    }
    // abs-sums for denominators (d = tx*4+j)
    #pragma unroll
    for (int j = 0; j < 4; ++j) {
      dq_local[j] += fabsf(accq[0][j]) + fabsf(accq[1][j]) +
                     fabsf(accq[2][j]) + fabsf(accq[3][j]);
      dk_local[j] += fabsf(acck[0][j]) + fabsf(acck[1][j]) +
                     fabsf(acck[2][j]) + fabsf(acck[3][j]);
    }
    // round-trip k,v through LDS for the outer product
    __syncthreads();
    #pragma unroll
    for (int i = 0; i < 4; ++i)
      #pragma unroll
      for (int j = 0; j < 4; ++j) {
        KVsub[(ty<<2)+i][(tx<<2)+j]      = acck[i][j];
        KVsub[(ty<<2)+i][64+(tx<<2)+j]   = accv[i][j];
      }
    __syncthreads();
    // kv_acc[d=ty*4+i][e=tx*4+j] += sum_t k[t][d]*v[t][e]
    for (int t = 0; t < 64; ++t) {
      float4 kk4 = *(const float4*)&KVsub[t][ty << 2];
      float4 vv4 = *(const float4*)&KVsub[t][64 + (tx << 2)];
      float kr[4] = {kk4.x, kk4.y, kk4.z, kk4.w};
      float vr[4] = {vv4.x, vv4.y, vv4.z, vv4.w};
      #pragma unroll
      for (int i = 0; i < 4; ++i)
        #pragma unroll
        for (int j = 0; j < 4; ++j)
          kv_acc[i][j] = fmaf(kr[i], vr[j], kv_acc[i][j]);
    }
  }
  // write kv partial
  float* ob = kvp + (size_t)bid * (HD * HD);
  #pragma unroll
  for (int i = 0; i < 4; ++i)
    *(float4*)&ob[((ty<<2)+i) * HD + (tx<<2)] =
        make_float4(kv_acc[i][0], kv_acc[i][1], kv_acc[i][2], kv_acc[i][3]);
  // reduce dq/dk across the 16 token-groups (reuse KVsub as scratch)
  float* red = &KVsub[0][0];
  __syncthreads();
  #pragma unroll
  for (int j = 0; j < 4; ++j) {
    red[ty * 64 + (tx<<2) + j]        = dq_local[j];
    red[1024 + ty * 64 + (tx<<2) + j] = dk_local[j];
  }
  __syncthreads();
  if (tid < 64) {
    float s = 0.f;
    #pragma unroll
    for (int g = 0; g < 16; ++g) s += red[g * 64 + tid];
    dqp[(size_t)bid * HD + tid] = s;
  } else if (tid < 128) {
    const int d = tid - 64;
    float s = 0.f;
    #pragma unroll
    for (int g = 0; g < 16; ++g) s += red[1024 + g * 64 + d];
    dkp[(size_t)bid * HD + d] = s;
  }
}

// ---------------------------------------------------------------------------
// Reduce partials, fold both L1 denominators:
// kvs[bh][d][e] = (sum_c kvp) / (max(dq,eps)*max(dk,eps))
// ---------------------------------------------------------------------------
__global__ __launch_bounds__(256)
void kv_reduce(const float* __restrict__ kvp, const float* __restrict__ dqp,
               const float* __restrict__ dkp, float* __restrict__ kvs) {
  const int bh = blockIdx.x;
  const int tid = threadIdx.x;
  __shared__ float dqL[64], dkL[64];
  if (tid < 64) {
    float s = 0.f;
    #pragma unroll
    for (int c = 0; c < NCHUNK; ++c) s += dqp[((size_t)bh * NCHUNK + c) * HD + tid];
    dqL[tid] = fmaxf(s, EPSN);
  } else if (tid < 128) {
    const int d = tid - 64;
    float s = 0.f;
    #pragma unroll
    for (int c = 0; c < NCHUNK; ++c) s += dkp[((size_t)bh * NCHUNK + c) * HD + d];
    dkL[d] = fmaxf(s, EPSN);
  }
  __syncthreads();
  #pragma unroll
  for (int i = 0; i < 16; ++i) {
    const int idx = i * 256 + tid;    // 0..4095
    const int d = idx >> 6;
    float s = 0.f;
    #pragma unroll
    for (int c = 0; c < NCHUNK; ++c)
      s += kvp[((size_t)bh * NCHUNK + c) * (HD * HD) + idx];
    kvs[(size_t)bh * (HD * HD) + idx] = s / (dqL[d] * dkL[d]);
  }
}

// ---------------------------------------------------------------------------
// W2[b][h*64+d][c] = sum_e kvs[bh][d][e] * w_proj[c][h*64+e]
// grid (96 bh, 6 c-tiles), tile [64 d x 128 c], K=64
// ---------------------------------------------------------------------------
__global__ __launch_bounds__(256)
void w2_kernel(const float* __restrict__ kvs, const float* __restrict__ w_proj,
               float* __restrict__ W2) {
  const int bh = blockIdx.x;
  const int b = bh / HEADS, h = bh % HEADS;
  const int c0 = blockIdx.y * 128;
  const int tid = threadIdx.x;
  const int tx = tid & 15, ty = tid >> 4;
  __shared__ float KVe[64][68];   // [e][d]
  __shared__ float Wp[64][132];   // [e][c]
  // stage full 64x64 kvs tile transposed: 1024 float4s = 4 per thread (FIXED)
  #pragma unroll
  for (int i = 0; i < 4; ++i) {
    const int idx = i * 256 + tid;        // 0..1023
    const int d  = idx >> 4;              // 0..63
    const int e4 = (idx & 15) << 2;       // 0..60
    float4 v4 = *(const float4*)&kvs[(size_t)bh * (HD*HD) + (size_t)d * HD + e4];
    KVe[e4+0][d] = v4.x; KVe[e4+1][d] = v4.y;
    KVe[e4+2][d] = v4.z; KVe[e4+3][d] = v4.w;
  }
  {
    const int c = tid >> 1, half = tid & 1;
    #pragma unroll
    for (int j = 0; j < 8; ++j) {
      const int e = half * 32 + j * 4;
      float4 v4 = *(const float4*)&w_proj[(size_t)(c0 + c) * DIMC + h * HD + e];
      Wp[e+0][c] = v4.x; Wp[e+1][c] = v4.y; Wp[e+2][c] = v4.z; Wp[e+3][c] = v4.w;
    }
  }
  __syncthreads();
  float acc[4][8] = {};
  for (int e = 0; e < 64; ++e) {
    float4 a4 = *(const float4*)&KVe[e][ty << 2];
    float4 b0 = *(const float4*)&Wp[e][tx << 3];
    float4 b1 = *(const float4*)&Wp[e][(tx << 3) + 4];
    float ar[4] = {a4.x, a4.y, a4.z, a4.w};
    float br[8] = {b0.x,b0.y,b0.z,b0.w,b1.x,b1.y,b1.z,b1.w};
    #pragma unroll
    for (int i = 0; i < 4; ++i)
      #pragma unroll
      for (int j = 0; j < 8; ++j)
        acc[i][j] = fmaf(ar[i], br[j], acc[i][j]);
  }
  float* W2b = W2 + (size_t)b * DIMC * DIMC;
  #pragma unroll
  for (int i = 0; i < 4; ++i) {
    const size_t row = (size_t)(h * HD + (ty<<2) + i) * DIMC + c0 + (tx<<3);
    *(float4*)&W2b[row]     = make_float4(acc[i][0], acc[i][1], acc[i][2], acc[i][3]);
    *(float4*)&W2b[row + 4] = make_float4(acc[i][4], acc[i][5], acc[i][6], acc[i][7]);
  }
}

// ---------------------------------------------------------------------------
// W3[b][m][c] = sum_k w_qkv[k][m] * W2[b][k][c]   (TN GEMM, both k-major)
// grid (6 m-tiles, 6 c-tiles, 8 b), tile 128x128, BK=16
// ---------------------------------------------------------------------------
__global__ __launch_bounds__(256)
void w3_kernel(const float* __restrict__ w_qkv, const float* __restrict__ W2,
               float* __restrict__ W3) {
  const int m0 = blockIdx.x * 128, c0 = blockIdx.y * 128, b = blockIdx.z;
  const float* Bb = W2 + (size_t)b * DIMC * DIMC;
  const int tid = threadIdx.x;
  const int tx = tid & 15, ty = tid >> 4;
  const int skk = tid >> 4, sc8 = (tid & 15) << 3;
  __shared__ float As[16][132];
  __shared__ float Bs[16][132];
  float acc[8][8] = {};
  for (int k0 = 0; k0 < DIMC; k0 += 16) {
    __syncthreads();
    *(float4*)&As[skk][sc8]     = *(const float4*)&w_qkv[(size_t)(k0+skk) * DIMC + m0 + sc8];
    *(float4*)&As[skk][sc8 + 4] = *(const float4*)&w_qkv[(size_t)(k0+skk) * DIMC + m0 + sc8 + 4];
    *(float4*)&Bs[skk][sc8]     = *(const float4*)&Bb[(size_t)(k0+skk) * DIMC + c0 + sc8];
    *(float4*)&Bs[skk][sc8 + 4] = *(const float4*)&Bb[(size_t)(k0+skk) * DIMC + c0 + sc8 + 4];
    __syncthreads();
    #pragma unroll
    for (int kk = 0; kk < 16; ++kk) {
      float4 a0 = *(const float4*)&As[kk][ty << 2];
      float4 a1 = *(const float4*)&As[kk][64 + (ty << 2)];
      float4 b0 = *(const float4*)&Bs[kk][tx << 2];
      float4 b1 = *(const float4*)&Bs[kk][64 + (tx << 2)];
      float ar[8] = {a0.x,a0.y,a0.z,a0.w,a1.x,a1.y,a1.z,a1.w};
      float br[8] = {b0.x,b0.y,b0.z,b0.w,b1.x,b1.y,b1.z,b1.w};
      #pragma unroll
      for (int i = 0; i < 8; ++i)
        #pragma unroll
        for (int j = 0; j < 8; ++j)
          acc[i][j] = fmaf(ar[i], br[j], acc[i][j]);
    }
  }
  float* Cb = W3 + (size_t)b * DIMC * DIMC;
  #pragma unroll
  for (int i = 0; i < 8; ++i) {
    const int r = m0 + ((i < 4) ? ((ty<<2) + i) : (64 + (ty<<2) + i - 4));
    #pragma unroll
    for (int jh = 0; jh < 2; ++jh) {
      const int cb = c0 + jh*64 + (tx<<2);
      *(float4*)&Cb[(size_t)r * DIMC + cb] =
          make_float4(acc[i][jh*4+0], acc[i][jh*4+1], acc[i][jh*4+2], acc[i][jh*4+3]);
    }
  }
}

// ---------------------------------------------------------------------------
// out[b][n][c] = sum_m x[b][n][m] * W3[b][m][c] + bias[c]   (NN GEMM)
// grid (32 n-tiles, 6 c-tiles, 8 b), tile 128x128, BK=16
// ---------------------------------------------------------------------------
__global__ __launch_bounds__(256)
void final_gemm(const float* __restrict__ x, const float* __restrict__ W3,
                const float* __restrict__ bias, float* __restrict__ out) {
  const int n0 = blockIdx.x * 128, c0 = blockIdx.y * 128, b = blockIdx.z;
  const float* Ab = x + (size_t)b * SEQ * DIMC;
  const float* Bb = W3 + (size_t)b * DIMC * DIMC;
  float* Cb = out + (size_t)b * SEQ * DIMC;
  const int tid = threadIdx.x;
  const int tx = tid & 15, ty = tid >> 4;
  const int lr = tid >> 2, lc4 = (tid & 3) << 2;
  const int skk = tid >> 4, sc8 = (tid & 15) << 3;
  __shared__ float As[16][132];
  __shared__ float Bs[16][132];
  float acc[8][8] = {};
  for (int k0 = 0; k0 < DIMC; k0 += 16) {
    __syncthreads();
    #pragma unroll
    for (int half = 0; half < 2; ++half) {
      const int r = lr + half * 64;
      float4 v4 = *(const float4*)&Ab[(size_t)(n0 + r) * DIMC + k0 + lc4];
      As[lc4+0][r] = v4.x; As[lc4+1][r] = v4.y;
      As[lc4+2][r] = v4.z; As[lc4+3][r] = v4.w;
    }
    *(float4*)&Bs[skk][sc8]     = *(const float4*)&Bb[(size_t)(k0+skk) * DIMC + c0 + sc8];
    *(float4*)&Bs[skk][sc8 + 4] = *(const float4*)&Bb[(size_t)(k0+skk) * DIMC + c0 + sc8 + 4];
    __syncthreads();
    #pragma unroll
    for (int kk = 0; kk < 16; ++kk) {
      float4 a0 = *(const float4*)&As[kk][ty << 2];
      float4 a1 = *(const float4*)&As[kk][64 + (ty << 2)];
      float4 b0 = *(const float4*)&Bs[kk][tx << 2];
      float4 b1 = *(const float4*)&Bs[kk][64 + (tx << 2)];
      float ar[8] = {a0.x,a0.y,a0.z,a0.w,a1.x,a1.y,a1.z,a1.w};
      float br[8] = {b0.x,b0.y,b0.z,b0.w,b1.x,b1.y,b1.z,b1.w};
      #pragma unroll
      for (int i = 0; i < 8; ++i)
        #pragma unroll
        for (int j = 0; j < 8; ++j)
          acc[i][j] = fmaf(ar[i], br[j], acc[i][j]);
    }
  }
  #pragma unroll
  for (int i = 0; i < 8; ++i) {
    const int r = n0 + ((i < 4) ? ((ty<<2) + i) : (64 + (ty<<2) + i - 4));
    #pragma unroll
    for (int jh = 0; jh < 2; ++jh) {
      const int cb = c0 + jh*64 + (tx<<2);
      float4 bv = *(const float4*)&bias[cb];
      *(float4*)&Cb[(size_t)r * DIMC + cb] =
          make_float4(acc[i][jh*4+0] + bv.x, acc[i][jh*4+1] + bv.y,
                      acc[i][jh*4+2] + bv.z, acc[i][jh*4+3] + bv.w);
    }
  }
}

// ---------------------------------------------------------------------------
extern "C" void kernel_launch(void* const* d_in, const int* in_sizes, int n_in,
                              void* d_out, int out_size, void* d_ws, size_t ws_size,
                              hipStream_t stream) {
  const float* x      = (const float*)d_in[0];
  const float* w_qkv  = (const float*)d_in[1];
  const float* w_proj = (const float*)d_in[2];
  const float* b_proj = (const float*)d_in[3];
  float* out = (float*)d_out;
  float* ws  = (float*)d_ws;

  // workspace layout (floats)
  const size_t KVP_SZ = (size_t)BHN * NCHUNK * HD * HD;  // 3,145,728
  const size_t DQP_SZ = (size_t)BHN * NCHUNK * HD;       // 49,152
  const size_t KVS_SZ = (size_t)BHN * HD * HD;           // 393,216
  const size_t W_SZ   = (size_t)BATCH * DIMC * DIMC;     // 4,718,592
  float* kvp = ws;
  float* dqp = kvp + KVP_SZ;
  float* dkp = dqp + DQP_SZ;
  float* kvs = dkp + DQP_SZ;
  float* W2  = kvs + KVS_SZ;
  float* W3  = W2 + W_SZ;
  const size_t need_bytes = (KVP_SZ + 2*DQP_SZ + KVS_SZ + 2*W_SZ) * sizeof(float);
  if (ws_size < need_bytes) return;   // clean validation failure, not a core dump

  const dim3 blk(256);
  qkv_stage1<<<dim3(BHN * NCHUNK), blk, 0, stream>>>(x, w_qkv, kvp, dqp, dkp);
  kv_reduce<<<dim3(BHN), blk, 0, stream>>>(kvp, dqp, dkp, kvs);
  w2_kernel<<<dim3(BHN, DIMC/128), blk, 0, stream>>>(kvs, w_proj, W2);
  w3_kernel<<<dim3(DIMC/128, DIMC/128, BATCH), blk, 0, stream>>>(w_qkv, W2, W3);
  final_gemm<<<dim3(SEQ/128, DIMC/128, BATCH), blk, 0, stream>>>(x, W3, b_proj, out);
}

// Round 4
// 2051.322 us; speedup vs baseline: 1.0327x; 1.0327x over previous
//
#include <hip/hip_runtime.h>
#include <cstddef>

#define DIMC   768
#define HEADS  12
#define HD     64
#define BATCH  8
#define SEQ    4096
#define MTOK   (BATCH*SEQ)     // 32768
#define THREEC (3*DIMC)        // 2304
#define BHN    (BATCH*HEADS)   // 96
#define NCHUNK 8               // token chunks per (b,h)
#define CHTOK  (SEQ/NCHUNK)    // 512 tokens per chunk
#define EPSN   1e-12f

// ---------------------------------------------------------------------------
// Stage 1: per (b, h, chunk) block, compute q,k,v for 512 tokens ON THE FLY
// (never stored to global), accumulate:
//   dqp[bid][d] = sum_tok |q|,  dkp[bid][d] = sum_tok |k|,
//   kvp[bid][d][e] = sum_tok k[t][d] * v[t][e]
// 8 sub-tiles of 64 tokens; per sub-tile a [64 tok x 192 out, K=768] GEMM.
// LDS: Xs/Ws (GEMM phase) UNIONed with KVsub (outer-product phase) — the two
// phases are barrier-separated, so 8448 floats total = 33 KB -> 4 blocks/CU.
// BK=32 halves the barrier count vs BK=16.
// ---------------------------------------------------------------------------
__global__ __launch_bounds__(256)
void qkv_stage1(const float* __restrict__ x, const float* __restrict__ w_qkv,
                float* __restrict__ kvp, float* __restrict__ dqp,
                float* __restrict__ dkp) {
  const int bid = blockIdx.x;
  const int bh = bid >> 3, chunk = bid & 7;
  const int b = bh / HEADS, h = bh % HEADS;
  const int tid = threadIdx.x;
  const int tx = tid & 15, ty = tid >> 4;
  const int lr = tid >> 2;            // 0..63: token row (X) / row-in-section (W)
  const int kc = (tid & 3) << 3;      // 0,8,16,24: k-offset within BK=32

  __shared__ float smem[8448];
  float (*Xs)[68]  = (float(*)[68])smem;            // [32][68]   (GEMM phase)
  float (*Ws)[196] = (float(*)[196])(smem + 2176);  // [32][196]  (GEMM phase)
  float (*KV)[132] = (float(*)[132])smem;           // [64][132]  (outer phase)

  float kv_acc[4][4] = {};
  float dq_local[4] = {}, dk_local[4] = {};

  for (int sub = 0; sub < 8; ++sub) {
    const float* xp = x + (size_t)(b * SEQ + chunk * CHTOK + sub * 64) * DIMC;
    float accq[4][4] = {}, acck[4][4] = {}, accv[4][4] = {};
    for (int k0 = 0; k0 < DIMC; k0 += 32) {
      __syncthreads();
      // stage X tile [64 tok x 32 k] transposed -> Xs[k][tok]
      {
        const float* px = &xp[(size_t)lr * DIMC + k0 + kc];
        float4 a0 = *(const float4*)px;
        float4 a1 = *(const float4*)(px + 4);
        Xs[kc+0][lr] = a0.x; Xs[kc+1][lr] = a0.y;
        Xs[kc+2][lr] = a0.z; Xs[kc+3][lr] = a0.w;
        Xs[kc+4][lr] = a1.x; Xs[kc+5][lr] = a1.y;
        Xs[kc+6][lr] = a1.z; Xs[kc+7][lr] = a1.w;
      }
      // stage W tile [192 out x 32 k] transposed (q,k,v sections)
      #pragma unroll
      for (int s = 0; s < 3; ++s) {
        const float* wp = w_qkv + (size_t)(s * DIMC + h * HD + lr) * DIMC + k0 + kc;
        float4 w0 = *(const float4*)wp;
        float4 w1 = *(const float4*)(wp + 4);
        const int c = s * 64 + lr;
        Ws[kc+0][c] = w0.x; Ws[kc+1][c] = w0.y;
        Ws[kc+2][c] = w0.z; Ws[kc+3][c] = w0.w;
        Ws[kc+4][c] = w1.x; Ws[kc+5][c] = w1.y;
        Ws[kc+6][c] = w1.z; Ws[kc+7][c] = w1.w;
      }
      __syncthreads();
      #pragma unroll
      for (int kk = 0; kk < 32; ++kk) {
        float4 a4 = *(const float4*)&Xs[kk][ty << 2];
        float4 q4 = *(const float4*)&Ws[kk][tx << 2];
        float4 k4 = *(const float4*)&Ws[kk][64 + (tx << 2)];
        float4 v4 = *(const float4*)&Ws[kk][128 + (tx << 2)];
        float ar[4] = {a4.x, a4.y, a4.z, a4.w};
        float qr[4] = {q4.x, q4.y, q4.z, q4.w};
        float kr[4] = {k4.x, k4.y, k4.z, k4.w};
        float vr[4] = {v4.x, v4.y, v4.z, v4.w};
        #pragma unroll
        for (int i = 0; i < 4; ++i)
          #pragma unroll
          for (int j = 0; j < 4; ++j) {
            accq[i][j] = fmaf(ar[i], qr[j], accq[i][j]);
            acck[i][j] = fmaf(ar[i], kr[j], acck[i][j]);
            accv[i][j] = fmaf(ar[i], vr[j], accv[i][j]);
          }
      }
    }
    // abs-sums for denominators (d = tx*4+j)
    #pragma unroll
    for (int j = 0; j < 4; ++j) {
      dq_local[j] += fabsf(accq[0][j]) + fabsf(accq[1][j]) +
                     fabsf(accq[2][j]) + fabsf(accq[3][j]);
      dk_local[j] += fabsf(acck[0][j]) + fabsf(acck[1][j]) +
                     fabsf(acck[2][j]) + fabsf(acck[3][j]);
    }
    // round-trip k,v through LDS (KV aliases Xs/Ws — barrier-separated)
    __syncthreads();
    #pragma unroll
    for (int i = 0; i < 4; ++i)
      #pragma unroll
      for (int j = 0; j < 4; ++j) {
        KV[(ty<<2)+i][(tx<<2)+j]    = acck[i][j];
        KV[(ty<<2)+i][64+(tx<<2)+j] = accv[i][j];
      }
    __syncthreads();
    // kv_acc[d=ty*4+i][e=tx*4+j] += sum_t k[t][d]*v[t][e]
    for (int t = 0; t < 64; ++t) {
      float4 kk4 = *(const float4*)&KV[t][ty << 2];
      float4 vv4 = *(const float4*)&KV[t][64 + (tx << 2)];
      float kr[4] = {kk4.x, kk4.y, kk4.z, kk4.w};
      float vr[4] = {vv4.x, vv4.y, vv4.z, vv4.w};
      #pragma unroll
      for (int i = 0; i < 4; ++i)
        #pragma unroll
        for (int j = 0; j < 4; ++j)
          kv_acc[i][j] = fmaf(kr[i], vr[j], kv_acc[i][j]);
    }
  }
  // write kv partial
  float* ob = kvp + (size_t)bid * (HD * HD);
  #pragma unroll
  for (int i = 0; i < 4; ++i)
    *(float4*)&ob[((ty<<2)+i) * HD + (tx<<2)] =
        make_float4(kv_acc[i][0], kv_acc[i][1], kv_acc[i][2], kv_acc[i][3]);
  // reduce dq/dk across the 16 token-groups (reuse smem as scratch)
  float* red = smem;
  __syncthreads();
  #pragma unroll
  for (int j = 0; j < 4; ++j) {
    red[ty * 64 + (tx<<2) + j]        = dq_local[j];
    red[1024 + ty * 64 + (tx<<2) + j] = dk_local[j];
  }
  __syncthreads();
  if (tid < 64) {
    float s = 0.f;
    #pragma unroll
    for (int g = 0; g < 16; ++g) s += red[g * 64 + tid];
    dqp[(size_t)bid * HD + tid] = s;
  } else if (tid < 128) {
    const int d = tid - 64;
    float s = 0.f;
    #pragma unroll
    for (int g = 0; g < 16; ++g) s += red[1024 + g * 64 + d];
    dkp[(size_t)bid * HD + d] = s;
  }
}

// ---------------------------------------------------------------------------
// Reduce partials, fold both L1 denominators:
// kvs[bh][d][e] = (sum_c kvp) / (max(dq,eps)*max(dk,eps))
// ---------------------------------------------------------------------------
__global__ __launch_bounds__(256)
void kv_reduce(const float* __restrict__ kvp, const float* __restrict__ dqp,
               const float* __restrict__ dkp, float* __restrict__ kvs) {
  const int bh = blockIdx.x;
  const int tid = threadIdx.x;
  __shared__ float dqL[64], dkL[64];
  if (tid < 64) {
    float s = 0.f;
    #pragma unroll
    for (int c = 0; c < NCHUNK; ++c) s += dqp[((size_t)bh * NCHUNK + c) * HD + tid];
    dqL[tid] = fmaxf(s, EPSN);
  } else if (tid < 128) {
    const int d = tid - 64;
    float s = 0.f;
    #pragma unroll
    for (int c = 0; c < NCHUNK; ++c) s += dkp[((size_t)bh * NCHUNK + c) * HD + d];
    dkL[d] = fmaxf(s, EPSN);
  }
  __syncthreads();
  #pragma unroll
  for (int i = 0; i < 16; ++i) {
    const int idx = i * 256 + tid;    // 0..4095
    const int d = idx >> 6;
    float s = 0.f;
    #pragma unroll
    for (int c = 0; c < NCHUNK; ++c)
      s += kvp[((size_t)bh * NCHUNK + c) * (HD * HD) + idx];
    kvs[(size_t)bh * (HD * HD) + idx] = s / (dqL[d] * dkL[d]);
  }
}

// ---------------------------------------------------------------------------
// W2[b][h*64+d][c] = sum_e kvs[bh][d][e] * w_proj[c][h*64+e]
// grid (96 bh, 6 c-tiles), tile [64 d x 128 c], K=64
// ---------------------------------------------------------------------------
__global__ __launch_bounds__(256)
void w2_kernel(const float* __restrict__ kvs, const float* __restrict__ w_proj,
               float* __restrict__ W2) {
  const int bh = blockIdx.x;
  const int b = bh / HEADS, h = bh % HEADS;
  const int c0 = blockIdx.y * 128;
  const int tid = threadIdx.x;
  const int tx = tid & 15, ty = tid >> 4;
  __shared__ float KVe[64][68];   // [e][d]
  __shared__ float Wp[64][132];   // [e][c]
  #pragma unroll
  for (int i = 0; i < 4; ++i) {
    const int idx = i * 256 + tid;        // 0..1023
    const int d  = idx >> 4;              // 0..63
    const int e4 = (idx & 15) << 2;       // 0..60
    float4 v4 = *(const float4*)&kvs[(size_t)bh * (HD*HD) + (size_t)d * HD + e4];
    KVe[e4+0][d] = v4.x; KVe[e4+1][d] = v4.y;
    KVe[e4+2][d] = v4.z; KVe[e4+3][d] = v4.w;
  }
  {
    const int c = tid >> 1, half = tid & 1;
    #pragma unroll
    for (int j = 0; j < 8; ++j) {
      const int e = half * 32 + j * 4;
      float4 v4 = *(const float4*)&w_proj[(size_t)(c0 + c) * DIMC + h * HD + e];
      Wp[e+0][c] = v4.x; Wp[e+1][c] = v4.y; Wp[e+2][c] = v4.z; Wp[e+3][c] = v4.w;
    }
  }
  __syncthreads();
  float acc[4][8] = {};
  for (int e = 0; e < 64; ++e) {
    float4 a4 = *(const float4*)&KVe[e][ty << 2];
    float4 b0 = *(const float4*)&Wp[e][tx << 3];
    float4 b1 = *(const float4*)&Wp[e][(tx << 3) + 4];
    float ar[4] = {a4.x, a4.y, a4.z, a4.w};
    float br[8] = {b0.x,b0.y,b0.z,b0.w,b1.x,b1.y,b1.z,b1.w};
    #pragma unroll
    for (int i = 0; i < 4; ++i)
      #pragma unroll
      for (int j = 0; j < 8; ++j)
        acc[i][j] = fmaf(ar[i], br[j], acc[i][j]);
  }
  float* W2b = W2 + (size_t)b * DIMC * DIMC;
  #pragma unroll
  for (int i = 0; i < 4; ++i) {
    const size_t row = (size_t)(h * HD + (ty<<2) + i) * DIMC + c0 + (tx<<3);
    *(float4*)&W2b[row]     = make_float4(acc[i][0], acc[i][1], acc[i][2], acc[i][3]);
    *(float4*)&W2b[row + 4] = make_float4(acc[i][4], acc[i][5], acc[i][6], acc[i][7]);
  }
}

// ---------------------------------------------------------------------------
// W3[b][m][c] = sum_k w_qkv[k][m] * W2[b][k][c]   (TN GEMM, both k-major)
// grid (6 m-tiles, 6 c-tiles, 8 b), tile 128x128, BK=16
// ---------------------------------------------------------------------------
__global__ __launch_bounds__(256)
void w3_kernel(const float* __restrict__ w_qkv, const float* __restrict__ W2,
               float* __restrict__ W3) {
  const int m0 = blockIdx.x * 128, c0 = blockIdx.y * 128, b = blockIdx.z;
  const float* Bb = W2 + (size_t)b * DIMC * DIMC;
  const int tid = threadIdx.x;
  const int tx = tid & 15, ty = tid >> 4;
  const int skk = tid >> 4, sc8 = (tid & 15) << 3;
  __shared__ float As[16][132];
  __shared__ float Bs[16][132];
  float acc[8][8] = {};
  for (int k0 = 0; k0 < DIMC; k0 += 16) {
    __syncthreads();
    *(float4*)&As[skk][sc8]     = *(const float4*)&w_qkv[(size_t)(k0+skk) * DIMC + m0 + sc8];
    *(float4*)&As[skk][sc8 + 4] = *(const float4*)&w_qkv[(size_t)(k0+skk) * DIMC + m0 + sc8 + 4];
    *(float4*)&Bs[skk][sc8]     = *(const float4*)&Bb[(size_t)(k0+skk) * DIMC + c0 + sc8];
    *(float4*)&Bs[skk][sc8 + 4] = *(const float4*)&Bb[(size_t)(k0+skk) * DIMC + c0 + sc8 + 4];
    __syncthreads();
    #pragma unroll
    for (int kk = 0; kk < 16; ++kk) {
      float4 a0 = *(const float4*)&As[kk][ty << 2];
      float4 a1 = *(const float4*)&As[kk][64 + (ty << 2)];
      float4 b0 = *(const float4*)&Bs[kk][tx << 2];
      float4 b1 = *(const float4*)&Bs[kk][64 + (tx << 2)];
      float ar[8] = {a0.x,a0.y,a0.z,a0.w,a1.x,a1.y,a1.z,a1.w};
      float br[8] = {b0.x,b0.y,b0.z,b0.w,b1.x,b1.y,b1.z,b1.w};
      #pragma unroll
      for (int i = 0; i < 8; ++i)
        #pragma unroll
        for (int j = 0; j < 8; ++j)
          acc[i][j] = fmaf(ar[i], br[j], acc[i][j]);
    }
  }
  float* Cb = W3 + (size_t)b * DIMC * DIMC;
  #pragma unroll
  for (int i = 0; i < 8; ++i) {
    const int r = m0 + ((i < 4) ? ((ty<<2) + i) : (64 + (ty<<2) + i - 4));
    #pragma unroll
    for (int jh = 0; jh < 2; ++jh) {
      const int cb = c0 + jh*64 + (tx<<2);
      *(float4*)&Cb[(size_t)r * DIMC + cb] =
          make_float4(acc[i][jh*4+0], acc[i][jh*4+1], acc[i][jh*4+2], acc[i][jh*4+3]);
    }
  }
}

// ---------------------------------------------------------------------------
// out[b][n][c] = sum_m x[b][n][m] * W3[b][m][c] + bias[c]   (NN GEMM)
// grid (32 n-tiles, 6 c-tiles, 8 b), tile 128x128, BK=16
// ---------------------------------------------------------------------------
__global__ __launch_bounds__(256)
void final_gemm(const float* __restrict__ x, const float* __restrict__ W3,
                const float* __restrict__ bias, float* __restrict__ out) {
  const int n0 = blockIdx.x * 128, c0 = blockIdx.y * 128, b = blockIdx.z;
  const float* Ab = x + (size_t)b * SEQ * DIMC;
  const float* Bb = W3 + (size_t)b * DIMC * DIMC;
  float* Cb = out + (size_t)b * SEQ * DIMC;
  const int tid = threadIdx.x;
  const int tx = tid & 15, ty = tid >> 4;
  const int lr = tid >> 2, lc4 = (tid & 3) << 2;
  const int skk = tid >> 4, sc8 = (tid & 15) << 3;
  __shared__ float As[16][132];
  __shared__ float Bs[16][132];
  float acc[8][8] = {};
  for (int k0 = 0; k0 < DIMC; k0 += 16) {
    __syncthreads();
    #pragma unroll
    for (int half = 0; half < 2; ++half) {
      const int r = lr + half * 64;
      float4 v4 = *(const float4*)&Ab[(size_t)(n0 + r) * DIMC + k0 + lc4];
      As[lc4+0][r] = v4.x; As[lc4+1][r] = v4.y;
      As[lc4+2][r] = v4.z; As[lc4+3][r] = v4.w;
    }
    *(float4*)&Bs[skk][sc8]     = *(const float4*)&Bb[(size_t)(k0+skk) * DIMC + c0 + sc8];
    *(float4*)&Bs[skk][sc8 + 4] = *(const float4*)&Bb[(size_t)(k0+skk) * DIMC + c0 + sc8 + 4];
    __syncthreads();
    #pragma unroll
    for (int kk = 0; kk < 16; ++kk) {
      float4 a0 = *(const float4*)&As[kk][ty << 2];
      float4 a1 = *(const float4*)&As[kk][64 + (ty << 2)];
      float4 b0 = *(const float4*)&Bs[kk][tx << 2];
      float4 b1 = *(const float4*)&Bs[kk][64 + (tx << 2)];
      float ar[8] = {a0.x,a0.y,a0.z,a0.w,a1.x,a1.y,a1.z,a1.w};
      float br[8] = {b0.x,b0.y,b0.z,b0.w,b1.x,b1.y,b1.z,b1.w};
      #pragma unroll
      for (int i = 0; i < 8; ++i)
        #pragma unroll
        for (int j = 0; j < 8; ++j)
          acc[i][j] = fmaf(ar[i], br[j], acc[i][j]);
    }
  }
  #pragma unroll
  for (int i = 0; i < 8; ++i) {
    const int r = n0 + ((i < 4) ? ((ty<<2) + i) : (64 + (ty<<2) + i - 4));
    #pragma unroll
    for (int jh = 0; jh < 2; ++jh) {
      const int cb = c0 + jh*64 + (tx<<2);
      float4 bv = *(const float4*)&bias[cb];
      *(float4*)&Cb[(size_t)r * DIMC + cb] =
          make_float4(acc[i][jh*4+0] + bv.x, acc[i][jh*4+1] + bv.y,
                      acc[i][jh*4+2] + bv.z, acc[i][jh*4+3] + bv.w);
    }
  }
}

// ---------------------------------------------------------------------------
extern "C" void kernel_launch(void* const* d_in, const int* in_sizes, int n_in,
                              void* d_out, int out_size, void* d_ws, size_t ws_size,
                              hipStream_t stream) {
  const float* x      = (const float*)d_in[0];
  const float* w_qkv  = (const float*)d_in[1];
  const float* w_proj = (const float*)d_in[2];
  const float* b_proj = (const float*)d_in[3];
  float* out = (float*)d_out;
  float* ws  = (float*)d_ws;

  // workspace layout (floats)
  const size_t KVP_SZ = (size_t)BHN * NCHUNK * HD * HD;  // 3,145,728
  const size_t DQP_SZ = (size_t)BHN * NCHUNK * HD;       // 49,152
  const size_t KVS_SZ = (size_t)BHN * HD * HD;           // 393,216
  const size_t W_SZ   = (size_t)BATCH * DIMC * DIMC;     // 4,718,592
  float* kvp = ws;
  float* dqp = kvp + KVP_SZ;
  float* dkp = dqp + DQP_SZ;
  float* kvs = dkp + DQP_SZ;
  float* W2  = kvs + KVS_SZ;
  float* W3  = W2 + W_SZ;
  const size_t need_bytes = (KVP_SZ + 2*DQP_SZ + KVS_SZ + 2*W_SZ) * sizeof(float);
  if (ws_size < need_bytes) return;   // clean validation failure, not a core dump

  const dim3 blk(256);
  qkv_stage1<<<dim3(BHN * NCHUNK), blk, 0, stream>>>(x, w_qkv, kvp, dqp, dkp);
  kv_reduce<<<dim3(BHN), blk, 0, stream>>>(kvp, dqp, dkp, kvs);
  w2_kernel<<<dim3(BHN, DIMC/128), blk, 0, stream>>>(kvs, w_proj, W2);
  w3_kernel<<<dim3(DIMC/128, DIMC/128, BATCH), blk, 0, stream>>>(w_qkv, W2, W3);
  final_gemm<<<dim3(SEQ/128, DIMC/128, BATCH), blk, 0, stream>>>(x, W3, b_proj, out);
}